// Round 1
// baseline (1801.797 us; speedup 1.0000x reference)
//
#include <hip/hip_runtime.h>

// GCN 2-layer, fp32 baseline.
// Layer: h = X@W; deg[i] = 1 + #incoming; dinv = rsqrt(deg);
//        agg[d] += h[s]*dinv[s]*dinv[d]  (over edges s->d)
//        out = agg + h*dinv^2 + b  (then relu for layer 1)

#define N_NODES 20000
#define N_EDGES 640000
#define IN_DIM 128
#define HID_DIM 128
#define OUT_DIM 64

__global__ void k_deg(const int* __restrict__ dst, float* __restrict__ deg) {
    int e = blockIdx.x * blockDim.x + threadIdx.x;
    if (e < N_EDGES) atomicAdd(&deg[dst[e]], 1.0f);
}

__global__ void k_dinv(const float* __restrict__ deg, float* __restrict__ dinv) {
    int i = blockIdx.x * blockDim.x + threadIdx.x;
    if (i < N_NODES) dinv[i] = rsqrtf(deg[i] + 1.0f);
}

// H[n, FOUT] = X[n, 128] @ W[128, FOUT].  Block = FOUT threads, 16 rows/block.
template <int FOUT>
__global__ void k_gemm(const float* __restrict__ X, const float* __restrict__ W,
                       float* __restrict__ H, int n_rows) {
    constexpr int ROWS = 16;
    __shared__ float xs[ROWS][IN_DIM];
    const int row0 = blockIdx.x * ROWS;
    const int f = threadIdx.x;

    for (int idx = f; idx < ROWS * IN_DIM; idx += FOUT) {
        int r = idx >> 7, k = idx & 127;
        int gr = row0 + r;
        xs[r][k] = (gr < n_rows) ? X[gr * IN_DIM + k] : 0.0f;
    }
    __syncthreads();

    float acc[ROWS];
#pragma unroll
    for (int r = 0; r < ROWS; ++r) acc[r] = 0.0f;

    for (int k = 0; k < IN_DIM; ++k) {
        float w = W[k * FOUT + f];
#pragma unroll
        for (int r = 0; r < ROWS; ++r) acc[r] += xs[r][k] * w;
    }

#pragma unroll
    for (int r = 0; r < ROWS; ++r) {
        int gr = row0 + r;
        if (gr < n_rows) H[gr * FOUT + f] = acc[r];
    }
}

// Per-edge scatter: agg[dst] += h[src] * dinv[src]*dinv[dst]
// One thread per (edge, 4-float chunk). F is 128 or 64 (power of 2).
template <int F>
__global__ void k_scatter(const int* __restrict__ src, const int* __restrict__ dst,
                          const float* __restrict__ dinv, const float* __restrict__ h,
                          float* __restrict__ agg) {
    constexpr int C = F / 4;           // chunks per edge
    int tid = blockIdx.x * blockDim.x + threadIdx.x;
    if (tid >= N_EDGES * C) return;
    int e = tid / C;
    int c = tid - e * C;
    int s = src[e];
    int d = dst[e];
    float w = dinv[s] * dinv[d];
    const float4 v = *(const float4*)(h + (long)s * F + c * 4);
    float* a = agg + (long)d * F + c * 4;
    atomicAdd(a + 0, v.x * w);
    atomicAdd(a + 1, v.y * w);
    atomicAdd(a + 2, v.z * w);
    atomicAdd(a + 3, v.w * w);
}

// out = agg + h*dinv^2 + b  (optional relu)
template <int F, bool RELU>
__global__ void k_combine(const float* __restrict__ agg, const float* __restrict__ h,
                          const float* __restrict__ dinv, const float* __restrict__ b,
                          float* __restrict__ out) {
    int idx = blockIdx.x * blockDim.x + threadIdx.x;
    if (idx >= N_NODES * F) return;
    int i = idx / F;
    int f = idx - i * F;
    float di = dinv[i];
    float v = agg[idx] + h[idx] * di * di + b[f];
    if (RELU) v = fmaxf(v, 0.0f);
    out[idx] = v;
}

extern "C" void kernel_launch(void* const* d_in, const int* in_sizes, int n_in,
                              void* d_out, int out_size, void* d_ws, size_t ws_size,
                              hipStream_t stream) {
    const float* x  = (const float*)d_in[0];
    const int*   ei = (const int*)d_in[1];
    const float* W1 = (const float*)d_in[2];
    const float* b1 = (const float*)d_in[3];
    const float* W2 = (const float*)d_in[4];
    const float* b2 = (const float*)d_in[5];

    const int* src = ei;             // edge_index[0]
    const int* dst = ei + N_EDGES;   // edge_index[1]

    float* ws   = (float*)d_ws;
    float* deg  = ws;                                   // 20000
    float* dinv = deg  + N_NODES;                       // 20000
    float* h1   = dinv + N_NODES;                       // 20000*128
    float* agg1 = h1   + (long)N_NODES * HID_DIM;       // 20000*128
    float* h1p  = agg1 + (long)N_NODES * HID_DIM;       // 20000*128
    float* h2   = h1p  + (long)N_NODES * HID_DIM;       // 20000*64
    float* agg2 = h2   + (long)N_NODES * OUT_DIM;       // 20000*64
    float* out  = (float*)d_out;

    hipMemsetAsync(deg,  0, N_NODES * sizeof(float), stream);
    hipMemsetAsync(agg1, 0, (size_t)N_NODES * HID_DIM * sizeof(float), stream);
    hipMemsetAsync(agg2, 0, (size_t)N_NODES * OUT_DIM * sizeof(float), stream);

    k_deg<<<(N_EDGES + 255) / 256, 256, 0, stream>>>(dst, deg);
    k_dinv<<<(N_NODES + 255) / 256, 256, 0, stream>>>(deg, dinv);

    // Layer 1
    k_gemm<HID_DIM><<<(N_NODES + 15) / 16, HID_DIM, 0, stream>>>(x, W1, h1, N_NODES);
    {
        long threads = (long)N_EDGES * (HID_DIM / 4);
        k_scatter<HID_DIM><<<(threads + 255) / 256, 256, 0, stream>>>(src, dst, dinv, h1, agg1);
    }
    k_combine<HID_DIM, true><<<(N_NODES * HID_DIM + 255) / 256, 256, 0, stream>>>(
        agg1, h1, dinv, b1, h1p);

    // Layer 2
    k_gemm<OUT_DIM><<<(N_NODES + 15) / 16, OUT_DIM, 0, stream>>>(h1p, W2, h2, N_NODES);
    {
        long threads = (long)N_EDGES * (OUT_DIM / 4);
        k_scatter<OUT_DIM><<<(threads + 255) / 256, 256, 0, stream>>>(src, dst, dinv, h2, agg2);
    }
    k_combine<OUT_DIM, false><<<(N_NODES * OUT_DIM + 255) / 256, 256, 0, stream>>>(
        agg2, h2, dinv, b2, out);
}

// Round 2
// 310.374 us; speedup vs baseline: 5.8052x; 5.8052x over previous
//
#include <hip/hip_runtime.h>

// GCN 2-layer, fp32. CSR-by-dst built per call (counting sort), then
// atomic-free per-node aggregation with fused self-loop + bias + relu.

#define N_NODES 20000
#define N_EDGES 640000
#define IN_DIM 128
#define HID_DIM 128
#define OUT_DIM 64

__global__ void k_deg(const int* __restrict__ dst, int* __restrict__ deg) {
    int e = blockIdx.x * blockDim.x + threadIdx.x;
    if (e < N_EDGES) atomicAdd(&deg[dst[e]], 1);
}

__global__ void k_dinv(const int* __restrict__ deg, float* __restrict__ dinv) {
    int i = blockIdx.x * blockDim.x + threadIdx.x;
    if (i < N_NODES) dinv[i] = rsqrtf((float)deg[i] + 1.0f);
}

// Exclusive prefix sum over N_NODES counts, single block of 1024 threads.
__global__ void k_scan(const int* __restrict__ cnt, int* __restrict__ rowptr) {
    __shared__ int partial[1024];
    const int t = threadIdx.x;
    constexpr int CHUNK = (N_NODES + 1023) / 1024;  // 20
    const int start = t * CHUNK;
    int sum = 0;
    for (int i = 0; i < CHUNK; ++i) {
        int idx = start + i;
        if (idx < N_NODES) sum += cnt[idx];
    }
    partial[t] = sum;
    __syncthreads();
    for (int off = 1; off < 1024; off <<= 1) {
        int v = (t >= off) ? partial[t - off] : 0;
        __syncthreads();
        partial[t] += v;
        __syncthreads();
    }
    int run = (t == 0) ? 0 : partial[t - 1];
    for (int i = 0; i < CHUNK; ++i) {
        int idx = start + i;
        if (idx < N_NODES) { rowptr[idx] = run; run += cnt[idx]; }
    }
    if (t == 1023) rowptr[N_NODES] = run;
}

__global__ void k_fill(const int* __restrict__ src, const int* __restrict__ dst,
                       const int* __restrict__ rowptr, int* __restrict__ cursor,
                       const float* __restrict__ dinv,
                       int* __restrict__ esrc, float* __restrict__ ewt) {
    int e = blockIdx.x * blockDim.x + threadIdx.x;
    if (e >= N_EDGES) return;
    int s = src[e], d = dst[e];
    int pos = rowptr[d] + atomicAdd(&cursor[d], 1);
    esrc[pos] = s;
    ewt[pos] = dinv[s] * dinv[d];
}

// H[n, FOUT] = X[n, 128] @ W[128, FOUT].  Block = FOUT threads, 16 rows/block.
template <int FOUT>
__global__ void k_gemm(const float* __restrict__ X, const float* __restrict__ W,
                       float* __restrict__ H, int n_rows) {
    constexpr int ROWS = 16;
    __shared__ float xs[ROWS][IN_DIM];
    const int row0 = blockIdx.x * ROWS;
    const int f = threadIdx.x;

    for (int idx = f; idx < ROWS * IN_DIM; idx += FOUT) {
        int r = idx >> 7, k = idx & 127;
        int gr = row0 + r;
        xs[r][k] = (gr < n_rows) ? X[gr * IN_DIM + k] : 0.0f;
    }
    __syncthreads();

    float acc[ROWS];
#pragma unroll
    for (int r = 0; r < ROWS; ++r) acc[r] = 0.0f;

    for (int k = 0; k < IN_DIM; ++k) {
        float w = W[k * FOUT + f];
#pragma unroll
        for (int r = 0; r < ROWS; ++r) acc[r] += xs[r][k] * w;
    }

#pragma unroll
    for (int r = 0; r < ROWS; ++r) {
        int gr = row0 + r;
        if (gr < n_rows) H[gr * FOUT + f] = acc[r];
    }
}

// One wave per node. Features striped across 64 lanes (NP = F/64 regs/lane).
// out[node] = sum_j ewt[j]*h[esrc[j]] + dinv[node]^2*h[node] + b, opt relu.
template <int F, bool RELU>
__global__ void k_agg(const int* __restrict__ rowptr, const int* __restrict__ esrc,
                      const float* __restrict__ ewt, const float* __restrict__ h,
                      const float* __restrict__ dinv, const float* __restrict__ b,
                      float* __restrict__ out) {
    constexpr int NP = F / 64;
    const int wave = threadIdx.x >> 6;      // 4 waves per block
    const int lane = threadIdx.x & 63;
    const int node = blockIdx.x * 4 + wave;
    if (node >= N_NODES) return;

    const int beg = rowptr[node], end = rowptr[node + 1];
    const float di = dinv[node];
    const float sw = di * di;

    float acc[NP];
#pragma unroll
    for (int p = 0; p < NP; ++p)
        acc[p] = h[(long)node * F + p * 64 + lane] * sw;

    int j = beg;
    // unroll-by-2 to expose more outstanding loads
    for (; j + 1 < end; j += 2) {
        int s0 = esrc[j], s1 = esrc[j + 1];
        float w0 = ewt[j], w1 = ewt[j + 1];
        const float* h0 = h + (long)s0 * F + lane;
        const float* h1 = h + (long)s1 * F + lane;
#pragma unroll
        for (int p = 0; p < NP; ++p) {
            float v0 = h0[p * 64];
            float v1 = h1[p * 64];
            acc[p] += v0 * w0 + v1 * w1;
        }
    }
    if (j < end) {
        int s = esrc[j];
        float w = ewt[j];
        const float* hp = h + (long)s * F + lane;
#pragma unroll
        for (int p = 0; p < NP; ++p) acc[p] += hp[p * 64] * w;
    }

#pragma unroll
    for (int p = 0; p < NP; ++p) {
        float v = acc[p] + b[p * 64 + lane];
        if (RELU) v = fmaxf(v, 0.0f);
        out[(long)node * F + p * 64 + lane] = v;
    }
}

extern "C" void kernel_launch(void* const* d_in, const int* in_sizes, int n_in,
                              void* d_out, int out_size, void* d_ws, size_t ws_size,
                              hipStream_t stream) {
    const float* x  = (const float*)d_in[0];
    const int*   ei = (const int*)d_in[1];
    const float* W1 = (const float*)d_in[2];
    const float* b1 = (const float*)d_in[3];
    const float* W2 = (const float*)d_in[4];
    const float* b2 = (const float*)d_in[5];

    const int* src = ei;             // edge_index[0]
    const int* dst = ei + N_EDGES;   // edge_index[1]

    char* w = (char*)d_ws;
    int*   deg    = (int*)w;                     w += sizeof(int) * N_NODES;
    int*   rowptr = (int*)w;                     w += sizeof(int) * (N_NODES + 1);
    int*   cursor = (int*)w;                     w += sizeof(int) * N_NODES;
    float* dinv   = (float*)w;                   w += sizeof(float) * N_NODES;
    int*   esrc   = (int*)w;                     w += sizeof(int) * N_EDGES;
    float* ewt    = (float*)w;                   w += sizeof(float) * N_EDGES;
    float* h1     = (float*)w;                   w += sizeof(float) * (size_t)N_NODES * HID_DIM;
    float* h1p    = (float*)w;                   w += sizeof(float) * (size_t)N_NODES * HID_DIM;
    float* h2     = (float*)w;                   w += sizeof(float) * (size_t)N_NODES * OUT_DIM;
    float* out    = (float*)d_out;

    hipMemsetAsync(deg, 0, sizeof(int) * N_NODES, stream);
    hipMemsetAsync(cursor, 0, sizeof(int) * N_NODES, stream);

    // CSR build
    k_deg<<<(N_EDGES + 255) / 256, 256, 0, stream>>>(dst, deg);
    k_dinv<<<(N_NODES + 255) / 256, 256, 0, stream>>>(deg, dinv);
    k_scan<<<1, 1024, 0, stream>>>(deg, rowptr);
    k_fill<<<(N_EDGES + 255) / 256, 256, 0, stream>>>(src, dst, rowptr, cursor, dinv, esrc, ewt);

    // Layer 1: h1 = x@W1 ; h1p = relu(Anorm*h1 + b1)
    k_gemm<HID_DIM><<<(N_NODES + 15) / 16, HID_DIM, 0, stream>>>(x, W1, h1, N_NODES);
    k_agg<HID_DIM, true><<<(N_NODES + 3) / 4, 256, 0, stream>>>(
        rowptr, esrc, ewt, h1, dinv, b1, h1p);

    // Layer 2: h2 = h1p@W2 ; out = Anorm*h2 + b2
    k_gemm<OUT_DIM><<<(N_NODES + 15) / 16, OUT_DIM, 0, stream>>>(h1p, W2, h2, N_NODES);
    k_agg<OUT_DIM, false><<<(N_NODES + 3) / 4, 256, 0, stream>>>(
        rowptr, esrc, ewt, h2, dinv, b2, out);
}

// Round 3
// 263.991 us; speedup vs baseline: 6.8252x; 1.1757x over previous
//
#include <hip/hip_runtime.h>
#include <hip/hip_fp16.h>

// GCN 2-layer. CSR by dst (counting sort) per call; fp32 GEMMs write fp16 h
// for the gather-heavy aggregation; aggregation is atomic-free, one wave/node,
// fused self-loop + bias + relu.

#define N_NODES 20000
#define N_EDGES 640000
#define IN_DIM 128
#define HID_DIM 128
#define OUT_DIM 64

__global__ void k_deg(const int* __restrict__ dst, int* __restrict__ deg) {
    int e = blockIdx.x * blockDim.x + threadIdx.x;
    if (e < N_EDGES) atomicAdd(&deg[dst[e]], 1);
}

// Exclusive prefix sum over N_NODES counts (one 1024-thread block).
// Also emits cursor copy (for k_fill's atomic cursors) and dinv.
__global__ void k_scan(const int* __restrict__ cnt, int* __restrict__ rowptr,
                       int* __restrict__ cursor, float* __restrict__ dinv) {
    __shared__ int partial[1024];
    const int t = threadIdx.x;
    constexpr int CHUNK = (N_NODES + 1023) / 1024;  // 20
    const int start = t * CHUNK;
    int sum = 0;
    for (int i = 0; i < CHUNK; ++i) {
        int idx = start + i;
        if (idx < N_NODES) sum += cnt[idx];
    }
    partial[t] = sum;
    __syncthreads();
    for (int off = 1; off < 1024; off <<= 1) {
        int v = (t >= off) ? partial[t - off] : 0;
        __syncthreads();
        partial[t] += v;
        __syncthreads();
    }
    int run = (t == 0) ? 0 : partial[t - 1];
    for (int i = 0; i < CHUNK; ++i) {
        int idx = start + i;
        if (idx < N_NODES) {
            int c = cnt[idx];
            rowptr[idx] = run;
            cursor[idx] = run;
            dinv[idx] = rsqrtf((float)c + 1.0f);
            run += c;
        }
    }
    if (t == 1023) rowptr[N_NODES] = run;
}

// meta[pos] = {src, weight} packed 8B. cursor pre-seeded with rowptr.
__global__ void k_fill(const int* __restrict__ src, const int* __restrict__ dst,
                       int* __restrict__ cursor, const float* __restrict__ dinv,
                       int2* __restrict__ meta) {
    int e = blockIdx.x * blockDim.x + threadIdx.x;
    if (e >= N_EDGES) return;
    int s = src[e], d = dst[e];
    int pos = atomicAdd(&cursor[d], 1);
    int2 m;
    m.x = s;
    m.y = __float_as_int(dinv[s] * dinv[d]);
    meta[pos] = m;
}

// H[32 rows x FOUT] per block = A[32x128] @ W[128xFOUT], fp32 math, fp16 out.
// 256 threads: tx in [0,16) covers CPT cols each, ty in [0,16) covers 2 rows.
template <int FOUT>
__global__ __launch_bounds__(256) void k_gemm(const float* __restrict__ A,
                                              const float* __restrict__ W,
                                              __half2* __restrict__ H2) {
    constexpr int CPT = FOUT / 16;  // cols per thread: 8 (F=128) or 4 (F=64)
    __shared__ float As[32][132];   // +4 pad: 16B-aligned rows, breaks ty-bank aliasing
    __shared__ float Bs[32][FOUT];

    const int tid = threadIdx.x;
    const int tx = tid & 15, ty = tid >> 4;
    const int row0 = blockIdx.x * 32;

    // stage A tile (32x128), coalesced float4 (20000 % 32 == 0: no guards)
#pragma unroll
    for (int i = 0; i < 4; ++i) {
        int idx = tid + 256 * i;
        int r = idx >> 5, c4 = (idx & 31) * 4;
        *(float4*)&As[r][c4] = *(const float4*)&A[(size_t)(row0 + r) * 128 + c4];
    }

    float acc[2][CPT];
#pragma unroll
    for (int r = 0; r < 2; ++r)
#pragma unroll
        for (int c = 0; c < CPT; ++c) acc[r][c] = 0.0f;

    for (int k0 = 0; k0 < 128; k0 += 32) {
        __syncthreads();
        // stage W chunk (32 x FOUT)
        constexpr int NV = 32 * FOUT / 4 / 256;  // float4s per thread: 4 or 2
#pragma unroll
        for (int i = 0; i < NV; ++i) {
            int idx = tid + 256 * i;
            int r = idx / (FOUT / 4), c4 = (idx % (FOUT / 4)) * 4;
            *(float4*)&Bs[r][c4] = *(const float4*)&W[(size_t)(k0 + r) * FOUT + c4];
        }
        __syncthreads();
#pragma unroll 8
        for (int kk = 0; kk < 32; ++kk) {
            float a0 = As[ty * 2 + 0][k0 + kk];
            float a1 = As[ty * 2 + 1][k0 + kk];
            float b[CPT];
            *(float4*)&b[0] = *(float4*)&Bs[kk][tx * CPT];
            if (CPT == 8) *(float4*)&b[4] = *(float4*)&Bs[kk][tx * CPT + 4];
#pragma unroll
            for (int c = 0; c < CPT; ++c) {
                acc[0][c] += a0 * b[c];
                acc[1][c] += a1 * b[c];
            }
        }
    }

#pragma unroll
    for (int r = 0; r < 2; ++r)
#pragma unroll
        for (int c = 0; c < CPT / 2; ++c) {
            int row = row0 + ty * 2 + r;
            H2[(size_t)row * (FOUT / 2) + tx * (CPT / 2) + c] =
                __floats2half2_rn(acc[r][2 * c], acc[r][2 * c + 1]);
        }
}

// F=128 aggregation: one wave per node, lane holds 2 features (half2 gather).
// out = sum_j w_j*h[s_j] + dinv^2*h[node] + b, optional relu. fp32 out.
template <bool RELU>
__global__ __launch_bounds__(256) void k_agg128(const int* __restrict__ rowptr,
                                                const int2* __restrict__ meta,
                                                const __half2* __restrict__ h,
                                                const float* __restrict__ dinv,
                                                const float* __restrict__ b,
                                                float2* __restrict__ out) {
    const int wave = threadIdx.x >> 6;
    const int lane = threadIdx.x & 63;
    const int node = blockIdx.x * 4 + wave;
    if (node >= N_NODES) return;

    const int beg = rowptr[node], end = rowptr[node + 1];
    const float di = dinv[node];
    const float sw = di * di;

    float2 fs = __half22float2(h[(size_t)node * 64 + lane]);
    float ax = fs.x * sw, ay = fs.y * sw;

    int j = beg;
    for (; j + 3 < end; j += 4) {
        int2 m0 = meta[j], m1 = meta[j + 1], m2 = meta[j + 2], m3 = meta[j + 3];
        __half2 g0 = h[(size_t)m0.x * 64 + lane];
        __half2 g1 = h[(size_t)m1.x * 64 + lane];
        __half2 g2 = h[(size_t)m2.x * 64 + lane];
        __half2 g3 = h[(size_t)m3.x * 64 + lane];
        float w0 = __int_as_float(m0.y), w1 = __int_as_float(m1.y);
        float w2 = __int_as_float(m2.y), w3 = __int_as_float(m3.y);
        float2 f0 = __half22float2(g0), f1 = __half22float2(g1);
        float2 f2 = __half22float2(g2), f3 = __half22float2(g3);
        ax += w0 * f0.x + w1 * f1.x + w2 * f2.x + w3 * f3.x;
        ay += w0 * f0.y + w1 * f1.y + w2 * f2.y + w3 * f3.y;
    }
    for (; j < end; ++j) {
        int2 m = meta[j];
        float w = __int_as_float(m.y);
        float2 f = __half22float2(h[(size_t)m.x * 64 + lane]);
        ax += w * f.x;
        ay += w * f.y;
    }

    ax += b[lane * 2 + 0];
    ay += b[lane * 2 + 1];
    if (RELU) { ax = fmaxf(ax, 0.0f); ay = fmaxf(ay, 0.0f); }
    float2 o; o.x = ax; o.y = ay;
    out[(size_t)node * 64 + lane] = o;
}

// F=64 aggregation: one wave per node, TWO edges per iteration
// (lanes 0-31: edge j, lanes 32-63: edge j+1), shfl_xor(32) fold at end.
__global__ __launch_bounds__(256) void k_agg64(const int* __restrict__ rowptr,
                                               const int2* __restrict__ meta,
                                               const __half2* __restrict__ h,
                                               const float* __restrict__ dinv,
                                               const float* __restrict__ b,
                                               float2* __restrict__ out) {
    const int wave = threadIdx.x >> 6;
    const int lane = threadIdx.x & 63;
    const int half_lo = (lane < 32);
    const int flane = lane & 31;
    const int node = blockIdx.x * 4 + wave;
    if (node >= N_NODES) return;

    const int beg = rowptr[node], end = rowptr[node + 1];
    const float di = dinv[node];
    const float sw = di * di;

    float ax = 0.0f, ay = 0.0f;
    if (half_lo) {
        float2 fs = __half22float2(h[(size_t)node * 32 + flane]);
        ax = fs.x * sw;
        ay = fs.y * sw;
    }

    int j = beg;
    for (; j + 3 < end; j += 4) {
        int2 m0 = meta[j], m1 = meta[j + 1], m2 = meta[j + 2], m3 = meta[j + 3];
        int sA = half_lo ? m0.x : m1.x;
        int sB = half_lo ? m2.x : m3.x;
        float wA = half_lo ? __int_as_float(m0.y) : __int_as_float(m1.y);
        float wB = half_lo ? __int_as_float(m2.y) : __int_as_float(m3.y);
        __half2 gA = h[(size_t)sA * 32 + flane];
        __half2 gB = h[(size_t)sB * 32 + flane];
        float2 fA = __half22float2(gA), fB = __half22float2(gB);
        ax += wA * fA.x + wB * fB.x;
        ay += wA * fA.y + wB * fB.y;
    }
    for (; j + 1 < end; j += 2) {
        int2 m0 = meta[j], m1 = meta[j + 1];
        int s = half_lo ? m0.x : m1.x;
        float w = half_lo ? __int_as_float(m0.y) : __int_as_float(m1.y);
        float2 f = __half22float2(h[(size_t)s * 32 + flane]);
        ax += w * f.x;
        ay += w * f.y;
    }
    if (j < end && half_lo) {
        int2 m = meta[j];
        float w = __int_as_float(m.y);
        float2 f = __half22float2(h[(size_t)m.x * 32 + flane]);
        ax += w * f.x;
        ay += w * f.y;
    }

    ax += __shfl_xor(ax, 32, 64);
    ay += __shfl_xor(ay, 32, 64);

    if (half_lo) {
        float2 o;
        o.x = ax + b[flane * 2 + 0];
        o.y = ay + b[flane * 2 + 1];
        out[(size_t)node * 32 + flane] = o;
    }
}

// relu(agg)+... is fused above; h1p stays fp32 as GEMM2's A input.
// k_agg128 with RELU writes fp32 float2 h1p.

extern "C" void kernel_launch(void* const* d_in, const int* in_sizes, int n_in,
                              void* d_out, int out_size, void* d_ws, size_t ws_size,
                              hipStream_t stream) {
    const float* x  = (const float*)d_in[0];
    const int*   ei = (const int*)d_in[1];
    const float* W1 = (const float*)d_in[2];
    const float* b1 = (const float*)d_in[3];
    const float* W2 = (const float*)d_in[4];
    const float* b2 = (const float*)d_in[5];

    const int* src = ei;             // edge_index[0]
    const int* dst = ei + N_EDGES;   // edge_index[1]

    char* w = (char*)d_ws;
    int2*    meta   = (int2*)w;      w += sizeof(int2) * N_EDGES;                     // 8B aligned at 0
    __half2* h1     = (__half2*)w;   w += sizeof(__half2) * (size_t)N_NODES * 64;     // 20000x128 fp16
    float*   h1p    = (float*)w;     w += sizeof(float) * (size_t)N_NODES * HID_DIM;  // fp32
    __half2* h2     = (__half2*)w;   w += sizeof(__half2) * (size_t)N_NODES * 32;     // 20000x64 fp16
    int*     deg    = (int*)w;       w += sizeof(int) * N_NODES;
    int*     rowptr = (int*)w;       w += sizeof(int) * (N_NODES + 2);
    int*     cursor = (int*)w;       w += sizeof(int) * N_NODES;
    float*   dinv   = (float*)w;     w += sizeof(float) * N_NODES;
    float*   out    = (float*)d_out;

    hipMemsetAsync(deg, 0, sizeof(int) * N_NODES, stream);

    // CSR build
    k_deg<<<(N_EDGES + 255) / 256, 256, 0, stream>>>(dst, deg);
    k_scan<<<1, 1024, 0, stream>>>(deg, rowptr, cursor, dinv);
    k_fill<<<(N_EDGES + 255) / 256, 256, 0, stream>>>(src, dst, cursor, dinv, meta);

    // Layer 1
    k_gemm<HID_DIM><<<N_NODES / 32, 256, 0, stream>>>(x, W1, h1);
    k_agg128<true><<<(N_NODES + 3) / 4, 256, 0, stream>>>(
        rowptr, meta, h1, dinv, b1, (float2*)h1p);

    // Layer 2
    k_gemm<OUT_DIM><<<N_NODES / 32, 256, 0, stream>>>(h1p, W2, h2);
    k_agg64<<<(N_NODES + 3) / 4, 256, 0, stream>>>(
        rowptr, meta, h2, dinv, b2, (float2*)out);
}

// Round 4
// 222.148 us; speedup vs baseline: 8.1108x; 1.1884x over previous
//
#include <hip/hip_runtime.h>
#include <hip/hip_fp16.h>

// GCN 2-layer. CSR by dst (counting sort) per call; fp32 GEMMs write fp16 h
// for the gather-heavy aggregation; aggregation is atomic-free, one wave/node,
// fused self-loop + bias + relu. Scan is 3-phase multi-block (R3: single-block
// scan was 47.7us on one CU).

#define N_NODES 20000
#define N_EDGES 640000
#define IN_DIM 128
#define HID_DIM 128
#define OUT_DIM 64

#define SCAN_NB ((N_NODES + 255) / 256)  // 79

__global__ void k_deg(const int* __restrict__ dst, int* __restrict__ deg) {
    int e = blockIdx.x * blockDim.x + threadIdx.x;
    if (e < N_EDGES) atomicAdd(&deg[dst[e]], 1);
}

// Phase 1: per-block sums of 256 counts.
__global__ __launch_bounds__(256) void k_bsum(const int* __restrict__ cnt,
                                              int* __restrict__ bsum) {
    int i = blockIdx.x * 256 + threadIdx.x;
    int c = (i < N_NODES) ? cnt[i] : 0;
    // wave reduce
    for (int off = 32; off > 0; off >>= 1) c += __shfl_down(c, off, 64);
    __shared__ int ws[4];
    int lane = threadIdx.x & 63, wv = threadIdx.x >> 6;
    if (lane == 0) ws[wv] = c;
    __syncthreads();
    if (threadIdx.x == 0)
        bsum[blockIdx.x] = ws[0] + ws[1] + ws[2] + ws[3];
}

// Phase 2: exclusive scan of SCAN_NB block sums (one small block).
__global__ __launch_bounds__(128) void k_bscan(const int* __restrict__ bsum,
                                               int* __restrict__ boff,
                                               int* __restrict__ rowptr) {
    __shared__ int s[128];
    int t = threadIdx.x;
    s[t] = (t < SCAN_NB) ? bsum[t] : 0;
    __syncthreads();
    for (int off = 1; off < 128; off <<= 1) {
        int v = (t >= off) ? s[t - off] : 0;
        __syncthreads();
        s[t] += v;
        __syncthreads();
    }
    if (t < SCAN_NB) boff[t] = (t == 0) ? 0 : s[t - 1];
    if (t == 0) rowptr[N_NODES] = N_EDGES;  // total is always E
}

// Phase 3: per-block exclusive scan + block offset -> rowptr/cursor/dinv.
__global__ __launch_bounds__(256) void k_final(const int* __restrict__ cnt,
                                               const int* __restrict__ boff,
                                               int* __restrict__ rowptr,
                                               int* __restrict__ cursor,
                                               float* __restrict__ dinv) {
    int t = threadIdx.x;
    int i = blockIdx.x * 256 + t;
    int c = (i < N_NODES) ? cnt[i] : 0;
    int lane = t & 63, wv = t >> 6;
    // wave inclusive scan
    int v = c;
    for (int off = 1; off < 64; off <<= 1) {
        int u = __shfl_up(v, off, 64);
        if (lane >= off) v += u;
    }
    __shared__ int ws[4];
    if (lane == 63) ws[wv] = v;
    __syncthreads();
    int wadd = 0;
    for (int k = 0; k < 4; ++k)
        if (k < wv) wadd += ws[k];
    int excl = v - c + wadd + boff[blockIdx.x];
    if (i < N_NODES) {
        rowptr[i] = excl;
        cursor[i] = excl;
        dinv[i] = rsqrtf((float)c + 1.0f);
    }
}

// meta[pos] = {src, weight} packed 8B. cursor pre-seeded with rowptr.
__global__ void k_fill(const int* __restrict__ src, const int* __restrict__ dst,
                       int* __restrict__ cursor, const float* __restrict__ dinv,
                       int2* __restrict__ meta) {
    int e = blockIdx.x * blockDim.x + threadIdx.x;
    if (e >= N_EDGES) return;
    int s = src[e], d = dst[e];
    int pos = atomicAdd(&cursor[d], 1);
    int2 m;
    m.x = s;
    m.y = __float_as_int(dinv[s] * dinv[d]);
    meta[pos] = m;
}

// H[32 rows x FOUT] per block = A[32x128] @ W[128xFOUT], fp32 math, fp16 out.
template <int FOUT>
__global__ __launch_bounds__(256) void k_gemm(const float* __restrict__ A,
                                              const float* __restrict__ W,
                                              __half2* __restrict__ H2) {
    constexpr int CPT = FOUT / 16;  // cols per thread: 8 (F=128) or 4 (F=64)
    __shared__ float As[32][132];
    __shared__ float Bs[32][FOUT];

    const int tid = threadIdx.x;
    const int tx = tid & 15, ty = tid >> 4;
    const int row0 = blockIdx.x * 32;

#pragma unroll
    for (int i = 0; i < 4; ++i) {
        int idx = tid + 256 * i;
        int r = idx >> 5, c4 = (idx & 31) * 4;
        *(float4*)&As[r][c4] = *(const float4*)&A[(size_t)(row0 + r) * 128 + c4];
    }

    float acc[2][CPT];
#pragma unroll
    for (int r = 0; r < 2; ++r)
#pragma unroll
        for (int c = 0; c < CPT; ++c) acc[r][c] = 0.0f;

    for (int k0 = 0; k0 < 128; k0 += 32) {
        __syncthreads();
        constexpr int NV = 32 * FOUT / 4 / 256;
#pragma unroll
        for (int i = 0; i < NV; ++i) {
            int idx = tid + 256 * i;
            int r = idx / (FOUT / 4), c4 = (idx % (FOUT / 4)) * 4;
            *(float4*)&Bs[r][c4] = *(const float4*)&W[(size_t)(k0 + r) * FOUT + c4];
        }
        __syncthreads();
#pragma unroll 8
        for (int kk = 0; kk < 32; ++kk) {
            float a0 = As[ty * 2 + 0][k0 + kk];
            float a1 = As[ty * 2 + 1][k0 + kk];
            float b[CPT];
            *(float4*)&b[0] = *(float4*)&Bs[kk][tx * CPT];
            if (CPT == 8) *(float4*)&b[4] = *(float4*)&Bs[kk][tx * CPT + 4];
#pragma unroll
            for (int c = 0; c < CPT; ++c) {
                acc[0][c] += a0 * b[c];
                acc[1][c] += a1 * b[c];
            }
        }
    }

#pragma unroll
    for (int r = 0; r < 2; ++r)
#pragma unroll
        for (int c = 0; c < CPT / 2; ++c) {
            int row = row0 + ty * 2 + r;
            H2[(size_t)row * (FOUT / 2) + tx * (CPT / 2) + c] =
                __floats2half2_rn(acc[r][2 * c], acc[r][2 * c + 1]);
        }
}

// F=128 aggregation: one wave per node, lane holds 2 features (half2 gather).
template <bool RELU>
__global__ __launch_bounds__(256) void k_agg128(const int* __restrict__ rowptr,
                                                const int2* __restrict__ meta,
                                                const __half2* __restrict__ h,
                                                const float* __restrict__ dinv,
                                                const float* __restrict__ b,
                                                float2* __restrict__ out) {
    const int wave = threadIdx.x >> 6;
    const int lane = threadIdx.x & 63;
    const int node = blockIdx.x * 4 + wave;
    if (node >= N_NODES) return;

    const int beg = rowptr[node], end = rowptr[node + 1];
    const float di = dinv[node];
    const float sw = di * di;

    float2 fs = __half22float2(h[(size_t)node * 64 + lane]);
    float ax = fs.x * sw, ay = fs.y * sw;

    int j = beg;
    for (; j + 3 < end; j += 4) {
        int2 m0 = meta[j], m1 = meta[j + 1], m2 = meta[j + 2], m3 = meta[j + 3];
        __half2 g0 = h[(size_t)m0.x * 64 + lane];
        __half2 g1 = h[(size_t)m1.x * 64 + lane];
        __half2 g2 = h[(size_t)m2.x * 64 + lane];
        __half2 g3 = h[(size_t)m3.x * 64 + lane];
        float w0 = __int_as_float(m0.y), w1 = __int_as_float(m1.y);
        float w2 = __int_as_float(m2.y), w3 = __int_as_float(m3.y);
        float2 f0 = __half22float2(g0), f1 = __half22float2(g1);
        float2 f2 = __half22float2(g2), f3 = __half22float2(g3);
        ax += w0 * f0.x + w1 * f1.x + w2 * f2.x + w3 * f3.x;
        ay += w0 * f0.y + w1 * f1.y + w2 * f2.y + w3 * f3.y;
    }
    for (; j < end; ++j) {
        int2 m = meta[j];
        float w = __int_as_float(m.y);
        float2 f = __half22float2(h[(size_t)m.x * 64 + lane]);
        ax += w * f.x;
        ay += w * f.y;
    }

    ax += b[lane * 2 + 0];
    ay += b[lane * 2 + 1];
    if (RELU) { ax = fmaxf(ax, 0.0f); ay = fmaxf(ay, 0.0f); }
    float2 o; o.x = ax; o.y = ay;
    out[(size_t)node * 64 + lane] = o;
}

// F=64 aggregation: one wave per node, two edges per iteration.
__global__ __launch_bounds__(256) void k_agg64(const int* __restrict__ rowptr,
                                               const int2* __restrict__ meta,
                                               const __half2* __restrict__ h,
                                               const float* __restrict__ dinv,
                                               const float* __restrict__ b,
                                               float2* __restrict__ out) {
    const int wave = threadIdx.x >> 6;
    const int lane = threadIdx.x & 63;
    const int half_lo = (lane < 32);
    const int flane = lane & 31;
    const int node = blockIdx.x * 4 + wave;
    if (node >= N_NODES) return;

    const int beg = rowptr[node], end = rowptr[node + 1];
    const float di = dinv[node];
    const float sw = di * di;

    float ax = 0.0f, ay = 0.0f;
    if (half_lo) {
        float2 fs = __half22float2(h[(size_t)node * 32 + flane]);
        ax = fs.x * sw;
        ay = fs.y * sw;
    }

    int j = beg;
    for (; j + 3 < end; j += 4) {
        int2 m0 = meta[j], m1 = meta[j + 1], m2 = meta[j + 2], m3 = meta[j + 3];
        int sA = half_lo ? m0.x : m1.x;
        int sB = half_lo ? m2.x : m3.x;
        float wA = half_lo ? __int_as_float(m0.y) : __int_as_float(m1.y);
        float wB = half_lo ? __int_as_float(m2.y) : __int_as_float(m3.y);
        __half2 gA = h[(size_t)sA * 32 + flane];
        __half2 gB = h[(size_t)sB * 32 + flane];
        float2 fA = __half22float2(gA), fB = __half22float2(gB);
        ax += wA * fA.x + wB * fB.x;
        ay += wA * fA.y + wB * fB.y;
    }
    for (; j + 1 < end; j += 2) {
        int2 m0 = meta[j], m1 = meta[j + 1];
        int s = half_lo ? m0.x : m1.x;
        float w = half_lo ? __int_as_float(m0.y) : __int_as_float(m1.y);
        float2 f = __half22float2(h[(size_t)s * 32 + flane]);
        ax += w * f.x;
        ay += w * f.y;
    }
    if (j < end && half_lo) {
        int2 m = meta[j];
        float w = __int_as_float(m.y);
        float2 f = __half22float2(h[(size_t)m.x * 32 + flane]);
        ax += w * f.x;
        ay += w * f.y;
    }

    ax += __shfl_xor(ax, 32, 64);
    ay += __shfl_xor(ay, 32, 64);

    if (half_lo) {
        float2 o;
        o.x = ax + b[flane * 2 + 0];
        o.y = ay + b[flane * 2 + 1];
        out[(size_t)node * 32 + flane] = o;
    }
}

extern "C" void kernel_launch(void* const* d_in, const int* in_sizes, int n_in,
                              void* d_out, int out_size, void* d_ws, size_t ws_size,
                              hipStream_t stream) {
    const float* x  = (const float*)d_in[0];
    const int*   ei = (const int*)d_in[1];
    const float* W1 = (const float*)d_in[2];
    const float* b1 = (const float*)d_in[3];
    const float* W2 = (const float*)d_in[4];
    const float* b2 = (const float*)d_in[5];

    const int* src = ei;             // edge_index[0]
    const int* dst = ei + N_EDGES;   // edge_index[1]

    char* w = (char*)d_ws;
    int2*    meta   = (int2*)w;      w += sizeof(int2) * N_EDGES;
    __half2* h1     = (__half2*)w;   w += sizeof(__half2) * (size_t)N_NODES * 64;
    float*   h1p    = (float*)w;     w += sizeof(float) * (size_t)N_NODES * HID_DIM;
    __half2* h2     = (__half2*)w;   w += sizeof(__half2) * (size_t)N_NODES * 32;
    int*     deg    = (int*)w;       w += sizeof(int) * N_NODES;
    int*     rowptr = (int*)w;       w += sizeof(int) * (N_NODES + 2);
    int*     cursor = (int*)w;       w += sizeof(int) * N_NODES;
    float*   dinv   = (float*)w;     w += sizeof(float) * N_NODES;
    int*     bsum   = (int*)w;       w += sizeof(int) * 128;
    int*     boff   = (int*)w;       w += sizeof(int) * 128;
    float*   out    = (float*)d_out;

    hipMemsetAsync(deg, 0, sizeof(int) * N_NODES, stream);

    // CSR build
    k_deg<<<(N_EDGES + 255) / 256, 256, 0, stream>>>(dst, deg);
    k_bsum<<<SCAN_NB, 256, 0, stream>>>(deg, bsum);
    k_bscan<<<1, 128, 0, stream>>>(bsum, boff, rowptr);
    k_final<<<SCAN_NB, 256, 0, stream>>>(deg, boff, rowptr, cursor, dinv);
    k_fill<<<(N_EDGES + 255) / 256, 256, 0, stream>>>(src, dst, cursor, dinv, meta);

    // Layer 1
    k_gemm<HID_DIM><<<N_NODES / 32, 256, 0, stream>>>(x, W1, h1);
    k_agg128<true><<<(N_NODES + 3) / 4, 256, 0, stream>>>(
        rowptr, meta, h1, dinv, b1, (float2*)h1p);

    // Layer 2
    k_gemm<OUT_DIM><<<N_NODES / 32, 256, 0, stream>>>(h1p, W2, h2);
    k_agg64<<<(N_NODES + 3) / 4, 256, 0, stream>>>(
        rowptr, meta, h2, dinv, b2, (float2*)out);
}

// Round 5
// 207.187 us; speedup vs baseline: 8.6965x; 1.0722x over previous
//
#include <hip/hip_runtime.h>

// GCN 2-layer. CSR by dst (counting sort) per call.
// GEMMs: MFMA 16x16x32_f16, no-LDS (A-frags direct from global w/ cvt,
// B-frags from pre-transposed fp16 WT[col][k]). fp32 accumulate.
// Aggregation: atomic-free, multi-edge-per-wave, 8B half4 gathers,
// shfl_xor fold, fused self-loop + bias + relu.

#define N_NODES 20000
#define N_EDGES 640000
#define IN_DIM 128
#define HID_DIM 128
#define OUT_DIM 64

#define SCAN_NB ((N_NODES + 255) / 256)  // 79

typedef _Float16 half4_t __attribute__((ext_vector_type(4)));
typedef _Float16 half8_t __attribute__((ext_vector_type(8)));
typedef float float4_t __attribute__((ext_vector_type(4)));

__global__ void k_deg(const int* __restrict__ dst, int* __restrict__ deg) {
    int e = blockIdx.x * blockDim.x + threadIdx.x;
    if (e < N_EDGES) atomicAdd(&deg[dst[e]], 1);
}

// Phase 1: per-block sums of 256 counts.
__global__ __launch_bounds__(256) void k_bsum(const int* __restrict__ cnt,
                                              int* __restrict__ bsum) {
    int i = blockIdx.x * 256 + threadIdx.x;
    int c = (i < N_NODES) ? cnt[i] : 0;
    for (int off = 32; off > 0; off >>= 1) c += __shfl_down(c, off, 64);
    __shared__ int ws[4];
    int lane = threadIdx.x & 63, wv = threadIdx.x >> 6;
    if (lane == 0) ws[wv] = c;
    __syncthreads();
    if (threadIdx.x == 0)
        bsum[blockIdx.x] = ws[0] + ws[1] + ws[2] + ws[3];
}

// Phase 2: exclusive scan of SCAN_NB block sums.
__global__ __launch_bounds__(128) void k_bscan(const int* __restrict__ bsum,
                                               int* __restrict__ boff,
                                               int* __restrict__ rowptr) {
    __shared__ int s[128];
    int t = threadIdx.x;
    s[t] = (t < SCAN_NB) ? bsum[t] : 0;
    __syncthreads();
    for (int off = 1; off < 128; off <<= 1) {
        int v = (t >= off) ? s[t - off] : 0;
        __syncthreads();
        s[t] += v;
        __syncthreads();
    }
    if (t < SCAN_NB) boff[t] = (t == 0) ? 0 : s[t - 1];
    if (t == 0) rowptr[N_NODES] = N_EDGES;
}

// Phase 3: per-block exclusive scan + block offset -> rowptr/cursor/dinv.
__global__ __launch_bounds__(256) void k_final(const int* __restrict__ cnt,
                                               const int* __restrict__ boff,
                                               int* __restrict__ rowptr,
                                               int* __restrict__ cursor,
                                               float* __restrict__ dinv) {
    int t = threadIdx.x;
    int i = blockIdx.x * 256 + t;
    int c = (i < N_NODES) ? cnt[i] : 0;
    int lane = t & 63, wv = t >> 6;
    int v = c;
    for (int off = 1; off < 64; off <<= 1) {
        int u = __shfl_up(v, off, 64);
        if (lane >= off) v += u;
    }
    __shared__ int ws[4];
    if (lane == 63) ws[wv] = v;
    __syncthreads();
    int wadd = 0;
    for (int k = 0; k < 4; ++k)
        if (k < wv) wadd += ws[k];
    int excl = v - c + wadd + boff[blockIdx.x];
    if (i < N_NODES) {
        rowptr[i] = excl;
        cursor[i] = excl;
        dinv[i] = rsqrtf((float)c + 1.0f);
    }
}

// meta[pos] = {src, weight}. cursor pre-seeded with rowptr.
__global__ void k_fill(const int* __restrict__ src, const int* __restrict__ dst,
                       int* __restrict__ cursor, const float* __restrict__ dinv,
                       int2* __restrict__ meta) {
    int e = blockIdx.x * blockDim.x + threadIdx.x;
    if (e >= N_EDGES) return;
    int s = src[e], d = dst[e];
    int pos = atomicAdd(&cursor[d], 1);
    int2 m;
    m.x = s;
    m.y = __float_as_int(dinv[s] * dinv[d]);
    meta[pos] = m;
}

// Transpose+cast both weight matrices to fp16 WT[col][k] (k contiguous).
__global__ __launch_bounds__(256) void k_wt(const float* __restrict__ W1,
                                            const float* __restrict__ W2,
                                            _Float16* __restrict__ WT1,
                                            _Float16* __restrict__ WT2) {
    int i = blockIdx.x * 256 + threadIdx.x;
    if (i < 128 * 128) {
        int c = i >> 7, k = i & 127;
        WT1[i] = (_Float16)W1[k * 128 + c];
    } else {
        int o = i - 128 * 128;
        if (o < 64 * 128) {
            int c = o >> 7, k = o & 127;
            WT2[o] = (_Float16)W2[k * 64 + c];
        }
    }
}

// GEMM1: h1[20000x128] = x[20000x128] @ W1, MFMA f16, A fp32->cvt, out fp16.
// One wave per 16-row strip; 4 waves/block. B-frags from WT (global, L2-hot).
__global__ __launch_bounds__(256) void k_mgemm1(const float* __restrict__ A,
                                                const _Float16* __restrict__ WT,
                                                _Float16* __restrict__ H) {
    const int wave = threadIdx.x >> 6;
    const int lane = threadIdx.x & 63;
    const int strip = blockIdx.x * 4 + wave;
    if (strip >= N_NODES / 16) return;
    const int row0 = strip * 16;
    const int mrow = row0 + (lane & 15);
    const int kq = (lane >> 4) * 8;

    half8_t af[4];
#pragma unroll
    for (int kc = 0; kc < 4; ++kc) {
        const float* ap = A + (size_t)mrow * 128 + kc * 32 + kq;
        float4_t f0 = *(const float4_t*)ap;
        float4_t f1 = *(const float4_t*)(ap + 4);
        half8_t h;
        h[0] = (_Float16)f0[0]; h[1] = (_Float16)f0[1];
        h[2] = (_Float16)f0[2]; h[3] = (_Float16)f0[3];
        h[4] = (_Float16)f1[0]; h[5] = (_Float16)f1[1];
        h[6] = (_Float16)f1[2]; h[7] = (_Float16)f1[3];
        af[kc] = h;
    }

    float4_t acc[8];
#pragma unroll
    for (int nt = 0; nt < 8; ++nt) acc[nt] = (float4_t)(0.0f);

#pragma unroll
    for (int nt = 0; nt < 8; ++nt) {
        const _Float16* wp = WT + (size_t)(nt * 16 + (lane & 15)) * 128 + kq;
#pragma unroll
        for (int kc = 0; kc < 4; ++kc) {
            half8_t bf = *(const half8_t*)(wp + kc * 32);
            acc[nt] = __builtin_amdgcn_mfma_f32_16x16x32_f16(af[kc], bf, acc[nt], 0, 0, 0);
        }
    }

#pragma unroll
    for (int nt = 0; nt < 8; ++nt) {
#pragma unroll
        for (int r = 0; r < 4; ++r) {
            int row = row0 + (lane >> 4) * 4 + r;
            H[(size_t)row * 128 + nt * 16 + (lane & 15)] = (_Float16)acc[nt][r];
        }
    }
}

// GEMM2: h2[20000x64] = h1p[20000x128] @ W2, A fp16 direct, out fp16.
__global__ __launch_bounds__(256) void k_mgemm2(const _Float16* __restrict__ A,
                                                const _Float16* __restrict__ WT,
                                                _Float16* __restrict__ H) {
    const int wave = threadIdx.x >> 6;
    const int lane = threadIdx.x & 63;
    const int strip = blockIdx.x * 4 + wave;
    if (strip >= N_NODES / 16) return;
    const int row0 = strip * 16;
    const int mrow = row0 + (lane & 15);
    const int kq = (lane >> 4) * 8;

    half8_t af[4];
#pragma unroll
    for (int kc = 0; kc < 4; ++kc)
        af[kc] = *(const half8_t*)(A + (size_t)mrow * 128 + kc * 32 + kq);

    float4_t acc[4];
#pragma unroll
    for (int nt = 0; nt < 4; ++nt) acc[nt] = (float4_t)(0.0f);

#pragma unroll
    for (int nt = 0; nt < 4; ++nt) {
        const _Float16* wp = WT + (size_t)(nt * 16 + (lane & 15)) * 128 + kq;
#pragma unroll
        for (int kc = 0; kc < 4; ++kc) {
            half8_t bf = *(const half8_t*)(wp + kc * 32);
            acc[nt] = __builtin_amdgcn_mfma_f32_16x16x32_f16(af[kc], bf, acc[nt], 0, 0, 0);
        }
    }

#pragma unroll
    for (int nt = 0; nt < 4; ++nt) {
#pragma unroll
        for (int r = 0; r < 4; ++r) {
            int row = row0 + (lane >> 4) * 4 + r;
            H[(size_t)row * 64 + nt * 16 + (lane & 15)] = (_Float16)acc[nt][r];
        }
    }
}

// F=128 aggregation: one wave/node, 2 edges per iter (lane>>5 selects edge),
// 8B half4 gathers, xor-32 fold. Writes fp16 (relu'd, biased) for GEMM2.
__global__ __launch_bounds__(256) void k_agg128(const int* __restrict__ rowptr,
                                                const int2* __restrict__ meta,
                                                const _Float16* __restrict__ h,
                                                const float* __restrict__ dinv,
                                                const float* __restrict__ bias,
                                                _Float16* __restrict__ out) {
    const int wave = threadIdx.x >> 6;
    const int lane = threadIdx.x & 63;
    const int node = blockIdx.x * 4 + wave;
    if (node >= N_NODES) return;
    const int eidx = lane >> 5;      // which edge of the pair
    const int flane = lane & 31;     // feature group: 4 halfs at flane*4

    const int beg = rowptr[node], end = rowptr[node + 1];
    const float di = dinv[node];
    const float sw = di * di;

    float acc0 = 0.f, acc1 = 0.f, acc2 = 0.f, acc3 = 0.f;
    if (lane < 32) {
        half4_t s = *(const half4_t*)(h + (size_t)node * 128 + flane * 4);
        acc0 = (float)s[0] * sw; acc1 = (float)s[1] * sw;
        acc2 = (float)s[2] * sw; acc3 = (float)s[3] * sw;
    }

    int j = beg;
    for (; j + 3 < end; j += 4) {
        int2 mA = meta[j + eidx];
        int2 mB = meta[j + 2 + eidx];
        half4_t gA = *(const half4_t*)(h + (size_t)mA.x * 128 + flane * 4);
        half4_t gB = *(const half4_t*)(h + (size_t)mB.x * 128 + flane * 4);
        float wA = __int_as_float(mA.y), wB = __int_as_float(mB.y);
        acc0 += wA * (float)gA[0] + wB * (float)gB[0];
        acc1 += wA * (float)gA[1] + wB * (float)gB[1];
        acc2 += wA * (float)gA[2] + wB * (float)gB[2];
        acc3 += wA * (float)gA[3] + wB * (float)gB[3];
    }
    for (; j < end; j += 2) {
        int idx = j + eidx;
        int2 m = meta[(idx < end) ? idx : (end - 1)];
        float w = (idx < end) ? __int_as_float(m.y) : 0.0f;
        half4_t g = *(const half4_t*)(h + (size_t)m.x * 128 + flane * 4);
        acc0 += w * (float)g[0]; acc1 += w * (float)g[1];
        acc2 += w * (float)g[2]; acc3 += w * (float)g[3];
    }

    acc0 += __shfl_xor(acc0, 32, 64);
    acc1 += __shfl_xor(acc1, 32, 64);
    acc2 += __shfl_xor(acc2, 32, 64);
    acc3 += __shfl_xor(acc3, 32, 64);

    if (lane < 32) {
        float4_t bb = *(const float4_t*)(bias + flane * 4);
        half4_t o;
        o[0] = (_Float16)fmaxf(acc0 + bb[0], 0.0f);
        o[1] = (_Float16)fmaxf(acc1 + bb[1], 0.0f);
        o[2] = (_Float16)fmaxf(acc2 + bb[2], 0.0f);
        o[3] = (_Float16)fmaxf(acc3 + bb[3], 0.0f);
        *(half4_t*)(out + (size_t)node * 128 + flane * 4) = o;
    }
}

// F=64 aggregation: one wave/node, 4 edges per iter (lane>>4 selects edge),
// 8B half4 gathers, xor-32 + xor-16 fold. Writes fp32 output + bias.
__global__ __launch_bounds__(256) void k_agg64(const int* __restrict__ rowptr,
                                               const int2* __restrict__ meta,
                                               const _Float16* __restrict__ h,
                                               const float* __restrict__ dinv,
                                               const float* __restrict__ bias,
                                               float* __restrict__ out) {
    const int wave = threadIdx.x >> 6;
    const int lane = threadIdx.x & 63;
    const int node = blockIdx.x * 4 + wave;
    if (node >= N_NODES) return;
    const int eidx = lane >> 4;      // which edge of the quad
    const int flane = lane & 15;     // feature group: 4 halfs at flane*4

    const int beg = rowptr[node], end = rowptr[node + 1];
    const float di = dinv[node];
    const float sw = di * di;

    float acc0 = 0.f, acc1 = 0.f, acc2 = 0.f, acc3 = 0.f;
    if (lane < 16) {
        half4_t s = *(const half4_t*)(h + (size_t)node * 64 + flane * 4);
        acc0 = (float)s[0] * sw; acc1 = (float)s[1] * sw;
        acc2 = (float)s[2] * sw; acc3 = (float)s[3] * sw;
    }

    int j = beg;
    for (; j + 7 < end; j += 8) {
        int2 mA = meta[j + eidx];
        int2 mB = meta[j + 4 + eidx];
        half4_t gA = *(const half4_t*)(h + (size_t)mA.x * 64 + flane * 4);
        half4_t gB = *(const half4_t*)(h + (size_t)mB.x * 64 + flane * 4);
        float wA = __int_as_float(mA.y), wB = __int_as_float(mB.y);
        acc0 += wA * (float)gA[0] + wB * (float)gB[0];
        acc1 += wA * (float)gA[1] + wB * (float)gB[1];
        acc2 += wA * (float)gA[2] + wB * (float)gB[2];
        acc3 += wA * (float)gA[3] + wB * (float)gB[3];
    }
    for (; j < end; j += 4) {
        int idx = j + eidx;
        int2 m = meta[(idx < end) ? idx : (end - 1)];
        float w = (idx < end) ? __int_as_float(m.y) : 0.0f;
        half4_t g = *(const half4_t*)(h + (size_t)m.x * 64 + flane * 4);
        acc0 += w * (float)g[0]; acc1 += w * (float)g[1];
        acc2 += w * (float)g[2]; acc3 += w * (float)g[3];
    }

    acc0 += __shfl_xor(acc0, 32, 64);
    acc1 += __shfl_xor(acc1, 32, 64);
    acc2 += __shfl_xor(acc2, 32, 64);
    acc3 += __shfl_xor(acc3, 32, 64);
    acc0 += __shfl_xor(acc0, 16, 64);
    acc1 += __shfl_xor(acc1, 16, 64);
    acc2 += __shfl_xor(acc2, 16, 64);
    acc3 += __shfl_xor(acc3, 16, 64);

    if (lane < 16) {
        float4_t bb = *(const float4_t*)(bias + flane * 4);
        float4_t o;
        o[0] = acc0 + bb[0]; o[1] = acc1 + bb[1];
        o[2] = acc2 + bb[2]; o[3] = acc3 + bb[3];
        *(float4_t*)(out + (size_t)node * 64 + flane * 4) = o;
    }
}

extern "C" void kernel_launch(void* const* d_in, const int* in_sizes, int n_in,
                              void* d_out, int out_size, void* d_ws, size_t ws_size,
                              hipStream_t stream) {
    const float* x  = (const float*)d_in[0];
    const int*   ei = (const int*)d_in[1];
    const float* W1 = (const float*)d_in[2];
    const float* b1 = (const float*)d_in[3];
    const float* W2 = (const float*)d_in[4];
    const float* b2 = (const float*)d_in[5];

    const int* src = ei;
    const int* dst = ei + N_EDGES;

    char* w = (char*)d_ws;
    int2*      meta   = (int2*)w;      w += sizeof(int2) * N_EDGES;
    _Float16*  h1     = (_Float16*)w;  w += sizeof(_Float16) * (size_t)N_NODES * HID_DIM;
    _Float16*  h1p    = (_Float16*)w;  w += sizeof(_Float16) * (size_t)N_NODES * HID_DIM;
    _Float16*  h2     = (_Float16*)w;  w += sizeof(_Float16) * (size_t)N_NODES * OUT_DIM;
    _Float16*  WT1    = (_Float16*)w;  w += sizeof(_Float16) * 128 * 128;
    _Float16*  WT2    = (_Float16*)w;  w += sizeof(_Float16) * 64 * 128;
    int*       deg    = (int*)w;       w += sizeof(int) * N_NODES;
    int*       rowptr = (int*)w;       w += sizeof(int) * (N_NODES + 2);
    int*       cursor = (int*)w;       w += sizeof(int) * N_NODES;
    float*     dinv   = (float*)w;     w += sizeof(float) * N_NODES;
    int*       bsum   = (int*)w;       w += sizeof(int) * 128;
    int*       boff   = (int*)w;       w += sizeof(int) * 128;
    float*     out    = (float*)d_out;

    hipMemsetAsync(deg, 0, sizeof(int) * N_NODES, stream);

    // CSR build + weight transpose
    k_deg<<<(N_EDGES + 255) / 256, 256, 0, stream>>>(dst, deg);
    k_wt<<<(128 * 128 + 64 * 128 + 255) / 256, 256, 0, stream>>>(W1, W2, WT1, WT2);
    k_bsum<<<SCAN_NB, 256, 0, stream>>>(deg, bsum);
    k_bscan<<<1, 128, 0, stream>>>(bsum, boff, rowptr);
    k_final<<<SCAN_NB, 256, 0, stream>>>(deg, boff, rowptr, cursor, dinv);
    k_fill<<<(N_EDGES + 255) / 256, 256, 0, stream>>>(src, dst, cursor, dinv, meta);

    // Layer 1
    k_mgemm1<<<(N_NODES / 16 + 3) / 4, 256, 0, stream>>>(x, WT1, h1);
    k_agg128<<<(N_NODES + 3) / 4, 256, 0, stream>>>(rowptr, meta, h1, dinv, b1, h1p);

    // Layer 2
    k_mgemm2<<<(N_NODES / 16 + 3) / 4, 256, 0, stream>>>(h1p, WT2, h2);
    k_agg64<<<(N_NODES + 3) / 4, 256, 0, stream>>>(rowptr, meta, h2, dinv, b2, out);
}

// Round 6
// 206.128 us; speedup vs baseline: 8.7411x; 1.0051x over previous
//
#include <hip/hip_runtime.h>

// GCN 2-layer. CSR by dst (counting sort) per call.
// GEMMs: MFMA 16x16x32_f16, no-LDS. Aggregation: atomic-free, 16B half8
// gathers, multi-edge waves, shfl_xor fold, fused self-loop + bias + relu.
// R6: scan fused to 1 kernel (block recomputes own prefix), wt fused into
// deg, 16B gather width (R5: 8B, 2x the iterations).

#define N_NODES 20000
#define N_EDGES 640000
#define IN_DIM 128
#define HID_DIM 128
#define OUT_DIM 64

#define SCAN_NB ((N_NODES + 255) / 256)  // 79
#define DEG_NB ((N_EDGES + 255) / 256)   // 2500
#define WT_NB ((128 * 128 + 64 * 128 + 255) / 256)  // 96

typedef _Float16 half8_t __attribute__((ext_vector_type(8)));
typedef float float4_t __attribute__((ext_vector_type(4)));

// Fused: blocks [0, DEG_NB) histogram dst; blocks [DEG_NB, DEG_NB+WT_NB)
// transpose+cast W1/W2 to fp16 WT[col][k].
__global__ void k_degwt(const int* __restrict__ dst, int* __restrict__ deg,
                        const float* __restrict__ W1, const float* __restrict__ W2,
                        _Float16* __restrict__ WT1, _Float16* __restrict__ WT2) {
    int b = blockIdx.x;
    if (b < DEG_NB) {
        int e = b * 256 + threadIdx.x;
        if (e < N_EDGES) atomicAdd(&deg[dst[e]], 1);
    } else {
        int i = (b - DEG_NB) * 256 + threadIdx.x;
        if (i < 128 * 128) {
            int c = i >> 7, k = i & 127;
            WT1[i] = (_Float16)W1[k * 128 + c];
        } else {
            int o = i - 128 * 128;
            if (o < 64 * 128) {
                int c = o >> 7, k = o & 127;
                WT2[o] = (_Float16)W2[k * 64 + c];
            }
        }
    }
}

// One-kernel scan: block b sums cnt[0, 256b) for its global offset (L2-hot),
// then intra-block exclusive scan -> rowptr/cursor/dinv.
__global__ __launch_bounds__(256) void k_scan(const int* __restrict__ cnt,
                                              int* __restrict__ rowptr,
                                              int* __restrict__ cursor,
                                              float* __restrict__ dinv) {
    const int b = blockIdx.x, t = threadIdx.x;
    const int lane = t & 63, wv = t >> 6;
    __shared__ int ws[4], ps[4];

    // global prefix for this block
    int pre = 0;
    for (int i = t; i < b * 256; i += 256) pre += cnt[i];
    for (int off = 32; off > 0; off >>= 1) pre += __shfl_down(pre, off, 64);
    if (lane == 0) ps[wv] = pre;

    // own count + intra-block inclusive scan
    int i = b * 256 + t;
    int c = (i < N_NODES) ? cnt[i] : 0;
    int v = c;
    for (int off = 1; off < 64; off <<= 1) {
        int u = __shfl_up(v, off, 64);
        if (lane >= off) v += u;
    }
    if (lane == 63) ws[wv] = v;
    __syncthreads();

    int block_pre = ps[0] + ps[1] + ps[2] + ps[3];
    int wadd = 0;
    for (int k = 0; k < 4; ++k)
        if (k < wv) wadd += ws[k];
    int excl = block_pre + wadd + (v - c);
    if (i < N_NODES) {
        rowptr[i] = excl;
        cursor[i] = excl;
        dinv[i] = rsqrtf((float)c + 1.0f);
    }
    if (b == SCAN_NB - 1 && t == 0) rowptr[N_NODES] = N_EDGES;
}

// meta[pos] = {src, weight}. cursor pre-seeded with rowptr.
__global__ void k_fill(const int* __restrict__ src, const int* __restrict__ dst,
                       int* __restrict__ cursor, const float* __restrict__ dinv,
                       int2* __restrict__ meta) {
    int e = blockIdx.x * blockDim.x + threadIdx.x;
    if (e >= N_EDGES) return;
    int s = src[e], d = dst[e];
    int pos = atomicAdd(&cursor[d], 1);
    int2 m;
    m.x = s;
    m.y = __float_as_int(dinv[s] * dinv[d]);
    meta[pos] = m;
}

// GEMM1: h1[20000x128] = x[20000x128] @ W1, MFMA f16, A fp32->cvt, out fp16.
__global__ __launch_bounds__(256) void k_mgemm1(const float* __restrict__ A,
                                                const _Float16* __restrict__ WT,
                                                _Float16* __restrict__ H) {
    const int wave = threadIdx.x >> 6;
    const int lane = threadIdx.x & 63;
    const int strip = blockIdx.x * 4 + wave;
    if (strip >= N_NODES / 16) return;
    const int row0 = strip * 16;
    const int mrow = row0 + (lane & 15);
    const int kq = (lane >> 4) * 8;

    half8_t af[4];
#pragma unroll
    for (int kc = 0; kc < 4; ++kc) {
        const float* ap = A + (size_t)mrow * 128 + kc * 32 + kq;
        float4_t f0 = *(const float4_t*)ap;
        float4_t f1 = *(const float4_t*)(ap + 4);
        half8_t h;
        h[0] = (_Float16)f0[0]; h[1] = (_Float16)f0[1];
        h[2] = (_Float16)f0[2]; h[3] = (_Float16)f0[3];
        h[4] = (_Float16)f1[0]; h[5] = (_Float16)f1[1];
        h[6] = (_Float16)f1[2]; h[7] = (_Float16)f1[3];
        af[kc] = h;
    }

    float4_t acc[8];
#pragma unroll
    for (int nt = 0; nt < 8; ++nt) acc[nt] = (float4_t)(0.0f);

#pragma unroll
    for (int nt = 0; nt < 8; ++nt) {
        const _Float16* wp = WT + (size_t)(nt * 16 + (lane & 15)) * 128 + kq;
#pragma unroll
        for (int kc = 0; kc < 4; ++kc) {
            half8_t bf = *(const half8_t*)(wp + kc * 32);
            acc[nt] = __builtin_amdgcn_mfma_f32_16x16x32_f16(af[kc], bf, acc[nt], 0, 0, 0);
        }
    }

#pragma unroll
    for (int nt = 0; nt < 8; ++nt) {
#pragma unroll
        for (int r = 0; r < 4; ++r) {
            int row = row0 + (lane >> 4) * 4 + r;
            H[(size_t)row * 128 + nt * 16 + (lane & 15)] = (_Float16)acc[nt][r];
        }
    }
}

// GEMM2: h2[20000x64] = h1p[20000x128] @ W2, A fp16 direct, out fp16.
__global__ __launch_bounds__(256) void k_mgemm2(const _Float16* __restrict__ A,
                                                const _Float16* __restrict__ WT,
                                                _Float16* __restrict__ H) {
    const int wave = threadIdx.x >> 6;
    const int lane = threadIdx.x & 63;
    const int strip = blockIdx.x * 4 + wave;
    if (strip >= N_NODES / 16) return;
    const int row0 = strip * 16;
    const int mrow = row0 + (lane & 15);
    const int kq = (lane >> 4) * 8;

    half8_t af[4];
#pragma unroll
    for (int kc = 0; kc < 4; ++kc)
        af[kc] = *(const half8_t*)(A + (size_t)mrow * 128 + kc * 32 + kq);

    float4_t acc[4];
#pragma unroll
    for (int nt = 0; nt < 4; ++nt) acc[nt] = (float4_t)(0.0f);

#pragma unroll
    for (int nt = 0; nt < 4; ++nt) {
        const _Float16* wp = WT + (size_t)(nt * 16 + (lane & 15)) * 128 + kq;
#pragma unroll
        for (int kc = 0; kc < 4; ++kc) {
            half8_t bf = *(const half8_t*)(wp + kc * 32);
            acc[nt] = __builtin_amdgcn_mfma_f32_16x16x32_f16(af[kc], bf, acc[nt], 0, 0, 0);
        }
    }

#pragma unroll
    for (int nt = 0; nt < 4; ++nt) {
#pragma unroll
        for (int r = 0; r < 4; ++r) {
            int row = row0 + (lane >> 4) * 4 + r;
            H[(size_t)row * 64 + nt * 16 + (lane & 15)] = (_Float16)acc[nt][r];
        }
    }
}

// F=128 agg: one wave/node, 4 edges/iter (16 lanes x half8 per row).
// xor-32 + xor-16 fold. Writes fp16 (relu'd, biased) for GEMM2.
__global__ __launch_bounds__(256) void k_agg128(const int* __restrict__ rowptr,
                                                const int2* __restrict__ meta,
                                                const _Float16* __restrict__ h,
                                                const float* __restrict__ dinv,
                                                const float* __restrict__ bias,
                                                _Float16* __restrict__ out) {
    const int wave = threadIdx.x >> 6;
    const int lane = threadIdx.x & 63;
    const int node = blockIdx.x * 4 + wave;
    if (node >= N_NODES) return;
    const int eidx = lane >> 4;      // which edge of the quad
    const int flane = lane & 15;     // 8 halfs at flane*8

    const int beg = rowptr[node], end = rowptr[node + 1];
    const float di = dinv[node];
    const float sw = di * di;

    float acc[8];
#pragma unroll
    for (int p = 0; p < 8; ++p) acc[p] = 0.0f;
    if (lane < 16) {
        half8_t s = *(const half8_t*)(h + (size_t)node * 128 + flane * 8);
#pragma unroll
        for (int p = 0; p < 8; ++p) acc[p] = (float)s[p] * sw;
    }

    int j = beg;
    for (; j + 3 < end; j += 4) {
        int2 m = meta[j + eidx];
        float w = __int_as_float(m.y);
        half8_t g = *(const half8_t*)(h + (size_t)m.x * 128 + flane * 8);
#pragma unroll
        for (int p = 0; p < 8; ++p) acc[p] += w * (float)g[p];
    }
    if (j < end) {  // masked tail (end >= 1 here)
        int idx = j + eidx;
        int safe = (idx < end) ? idx : (end - 1);
        int2 m = meta[safe];
        float w = (idx < end) ? __int_as_float(m.y) : 0.0f;
        half8_t g = *(const half8_t*)(h + (size_t)m.x * 128 + flane * 8);
#pragma unroll
        for (int p = 0; p < 8; ++p) acc[p] += w * (float)g[p];
    }

#pragma unroll
    for (int p = 0; p < 8; ++p) {
        acc[p] += __shfl_xor(acc[p], 32, 64);
        acc[p] += __shfl_xor(acc[p], 16, 64);
    }

    if (lane < 16) {
        float4_t b0 = *(const float4_t*)(bias + flane * 8);
        float4_t b1 = *(const float4_t*)(bias + flane * 8 + 4);
        half8_t o;
        o[0] = (_Float16)fmaxf(acc[0] + b0[0], 0.0f);
        o[1] = (_Float16)fmaxf(acc[1] + b0[1], 0.0f);
        o[2] = (_Float16)fmaxf(acc[2] + b0[2], 0.0f);
        o[3] = (_Float16)fmaxf(acc[3] + b0[3], 0.0f);
        o[4] = (_Float16)fmaxf(acc[4] + b1[0], 0.0f);
        o[5] = (_Float16)fmaxf(acc[5] + b1[1], 0.0f);
        o[6] = (_Float16)fmaxf(acc[6] + b1[2], 0.0f);
        o[7] = (_Float16)fmaxf(acc[7] + b1[3], 0.0f);
        *(half8_t*)(out + (size_t)node * 128 + flane * 8) = o;
    }
}

// F=64 agg: one wave/node, 8 edges/iter (8 lanes x half8 per row).
// xor-32/16/8 fold. Writes fp32 output + bias.
__global__ __launch_bounds__(256) void k_agg64(const int* __restrict__ rowptr,
                                               const int2* __restrict__ meta,
                                               const _Float16* __restrict__ h,
                                               const float* __restrict__ dinv,
                                               const float* __restrict__ bias,
                                               float* __restrict__ out) {
    const int wave = threadIdx.x >> 6;
    const int lane = threadIdx.x & 63;
    const int node = blockIdx.x * 4 + wave;
    if (node >= N_NODES) return;
    const int eidx = lane >> 3;      // which edge of the oct
    const int flane = lane & 7;      // 8 halfs at flane*8

    const int beg = rowptr[node], end = rowptr[node + 1];
    const float di = dinv[node];
    const float sw = di * di;

    float acc[8];
#pragma unroll
    for (int p = 0; p < 8; ++p) acc[p] = 0.0f;
    if (lane < 8) {
        half8_t s = *(const half8_t*)(h + (size_t)node * 64 + flane * 8);
#pragma unroll
        for (int p = 0; p < 8; ++p) acc[p] = (float)s[p] * sw;
    }

    int j = beg;
    for (; j + 7 < end; j += 8) {
        int2 m = meta[j + eidx];
        float w = __int_as_float(m.y);
        half8_t g = *(const half8_t*)(h + (size_t)m.x * 64 + flane * 8);
#pragma unroll
        for (int p = 0; p < 8; ++p) acc[p] += w * (float)g[p];
    }
    if (j < end) {
        int idx = j + eidx;
        int safe = (idx < end) ? idx : (end - 1);
        int2 m = meta[safe];
        float w = (idx < end) ? __int_as_float(m.y) : 0.0f;
        half8_t g = *(const half8_t*)(h + (size_t)m.x * 64 + flane * 8);
#pragma unroll
        for (int p = 0; p < 8; ++p) acc[p] += w * (float)g[p];
    }

#pragma unroll
    for (int p = 0; p < 8; ++p) {
        acc[p] += __shfl_xor(acc[p], 32, 64);
        acc[p] += __shfl_xor(acc[p], 16, 64);
        acc[p] += __shfl_xor(acc[p], 8, 64);
    }

    if (lane < 8) {
        float4_t b0 = *(const float4_t*)(bias + flane * 8);
        float4_t b1 = *(const float4_t*)(bias + flane * 8 + 4);
        float4_t o0, o1;
        o0[0] = acc[0] + b0[0]; o0[1] = acc[1] + b0[1];
        o0[2] = acc[2] + b0[2]; o0[3] = acc[3] + b0[3];
        o1[0] = acc[4] + b1[0]; o1[1] = acc[5] + b1[1];
        o1[2] = acc[6] + b1[2]; o1[3] = acc[7] + b1[3];
        *(float4_t*)(out + (size_t)node * 64 + flane * 8) = o0;
        *(float4_t*)(out + (size_t)node * 64 + flane * 8 + 4) = o1;
    }
}

extern "C" void kernel_launch(void* const* d_in, const int* in_sizes, int n_in,
                              void* d_out, int out_size, void* d_ws, size_t ws_size,
                              hipStream_t stream) {
    const float* x  = (const float*)d_in[0];
    const int*   ei = (const int*)d_in[1];
    const float* W1 = (const float*)d_in[2];
    const float* b1 = (const float*)d_in[3];
    const float* W2 = (const float*)d_in[4];
    const float* b2 = (const float*)d_in[5];

    const int* src = ei;
    const int* dst = ei + N_EDGES;

    char* w = (char*)d_ws;
    int2*      meta   = (int2*)w;      w += sizeof(int2) * N_EDGES;
    _Float16*  h1     = (_Float16*)w;  w += sizeof(_Float16) * (size_t)N_NODES * HID_DIM;
    _Float16*  h1p    = (_Float16*)w;  w += sizeof(_Float16) * (size_t)N_NODES * HID_DIM;
    _Float16*  h2     = (_Float16*)w;  w += sizeof(_Float16) * (size_t)N_NODES * OUT_DIM;
    _Float16*  WT1    = (_Float16*)w;  w += sizeof(_Float16) * 128 * 128;
    _Float16*  WT2    = (_Float16*)w;  w += sizeof(_Float16) * 64 * 128;
    int*       deg    = (int*)w;       w += sizeof(int) * N_NODES;
    int*       rowptr = (int*)w;       w += sizeof(int) * (N_NODES + 2);
    int*       cursor = (int*)w;       w += sizeof(int) * N_NODES;
    float*     dinv   = (float*)w;     w += sizeof(float) * N_NODES;
    float*     out    = (float*)d_out;

    hipMemsetAsync(deg, 0, sizeof(int) * N_NODES, stream);

    // CSR build + weight transpose
    k_degwt<<<DEG_NB + WT_NB, 256, 0, stream>>>(dst, deg, W1, W2, WT1, WT2);
    k_scan<<<SCAN_NB, 256, 0, stream>>>(deg, rowptr, cursor, dinv);
    k_fill<<<(N_EDGES + 255) / 256, 256, 0, stream>>>(src, dst, cursor, dinv, meta);

    // Layer 1
    k_mgemm1<<<(N_NODES / 16 + 3) / 4, 256, 0, stream>>>(x, WT1, h1);
    k_agg128<<<(N_NODES + 3) / 4, 256, 0, stream>>>(rowptr, meta, h1, dinv, b1, h1p);

    // Layer 2
    k_mgemm2<<<(N_NODES / 16 + 3) / 4, 256, 0, stream>>>(h1p, WT2, h2);
    k_agg64<<<(N_NODES + 3) / 4, 256, 0, stream>>>(rowptr, meta, h2, dinv, b2, out);
}